// Round 4
// baseline (309.978 us; speedup 1.0000x reference)
//
#include <hip/hip_runtime.h>
#include <hip/hip_bf16.h>
#include <math.h>

// Problem constants (fixed shapes from setup_inputs)
#define B_   16
#define F_   2048
#define N_   64
#define K_   1024   // F/2
#define YP   2056   // padded LDS row stride (ushorts) — fused fallback only

typedef short bf16x8 __attribute__((ext_vector_type(8)));  // 8 bf16 = 4 VGPR
typedef float v4f    __attribute__((ext_vector_type(4)));  // MFMA C/D frag

__device__ __forceinline__ float wave_sum(float v) {
#pragma unroll
  for (int off = 32; off > 0; off >>= 1) v += __shfl_down(v, off, 64);
  return v;
}
__device__ __forceinline__ float wave_max(float v) {
#pragma unroll
  for (int off = 32; off > 0; off >>= 1) v = fmaxf(v, __shfl_down(v, off, 64));
  return v;
}

// fp32 -> bf16 bits, round-to-nearest-even (finite inputs only)
__device__ __forceinline__ unsigned f2bf(float x) {
  const unsigned u = __float_as_uint(x);
  return (u + 0x7FFFu + ((u >> 16) & 1u)) >> 16;
}
__device__ __forceinline__ float bf2f(unsigned us) {
  return __uint_as_float(us << 16);
}
// 16-bit total-order inverse: ord -> bf16 bits
__device__ __forceinline__ unsigned ord2u16(unsigned T) {
  return (T & 0x8000u) ? (T ^ 0x8000u) : (T ^ 0xFFFFu);
}
// packed pair of ord16 keys from a dword of 2 bf16 values
__device__ __forceinline__ unsigned ordpair(unsigned wd) {
  return wd ^ (0x80008000u | (((wd & 0x80008000u) >> 15) * 0x7FFFu));
}

// K0: per-(b,n) feature stats, ATOMIC-FREE (unchanged, verified).
__global__ __launch_bounds__(256) void stats_kernel(
    const float* __restrict__ X, const float* __restrict__ M,
    float* __restrict__ P) {
  __shared__ float red[4][N_][4];   // [fi][n][word], 4 KB
  const int tid = threadIdx.x;
  const int b = blockIdx.x >> 4;
  const int fb = blockIdx.x & 15;
  const int f0 = fb * 128;
  const int fi = tid >> 6, n = tid & 63;
  float sx = 0.f, sxx = 0.f, sm = 0.f, smm = 0.f;
#pragma unroll 4
  for (int j = 0; j < 32; ++j) {
    const int f = f0 + fi + 4 * j;
    const size_t gi = ((size_t)b * F_ + f) * N_ + n;
    const float x = X[gi];
    const float m = M[gi];
    sx += x; sxx += x * x; sm += m; smm += m * m;
  }
  red[fi][n][0] = sx; red[fi][n][1] = sxx;
  red[fi][n][2] = sm; red[fi][n][3] = smm;
  __syncthreads();
  const int wn = tid & 63, word = tid >> 6;
  const float s = red[0][wn][word] + red[1][wn][word] +
                  red[2][wn][word] + red[3][wn][word];
  P[(((size_t)b * N_ + wn) * 4 + word) * 16 + fb] = s;
}

// K1: center + L2-normalize per (b,n); write bf16 (unchanged, verified).
__global__ __launch_bounds__(256) void normbf_kernel(
    const float* __restrict__ X, const float* __restrict__ M,
    const float* __restrict__ P,
    short* __restrict__ Xb16, short* __restrict__ Mb16) {
  const int tid = threadIdx.x;
  const int b = blockIdx.x >> 4;
  const int f0 = (blockIdx.x & 15) * 128;
  const int n = tid & 63;
  const float* base = P + (((size_t)b * N_ + n) * 4) * 16;
  float acc4[4];
#pragma unroll
  for (int wj = 0; wj < 4; ++wj) {
    float s = 0.f;
#pragma unroll
    for (int i = 0; i < 16; ++i) s += base[16 * wj + i];
    acc4[wj] = s;
  }
  const float sx = acc4[0], sxx = acc4[1], sm = acc4[2], smm = acc4[3];
  const float mux = sx * (1.f / F_), mum = sm * (1.f / F_);
  const float rx = 1.f / (sqrtf(fmaxf(sxx - (float)F_ * mux * mux, 0.f)) + 1e-10f);
  const float rm = 1.f / (sqrtf(fmaxf(smm - (float)F_ * mum * mum, 0.f)) + 1e-10f);
#pragma unroll 4
  for (int jj = 0; jj < 32; ++jj) {
    const int f = f0 + (tid >> 6) + 4 * jj;
    const size_t gi = ((size_t)b * F_ + f) * N_ + n;
    Xb16[gi] = (short)f2bf((X[gi] - mux) * rx);
    Mb16[gi] = (short)f2bf((M[gi] - mum) * rm);
  }
}

// K2a: GEMM only — same MFMA tiling/rounding as the fused kernel, but
// stores the 16x2048 bf16 row-block to global YXg instead of LDS. No LDS,
// no selection => pure MFMA/store kernel. local_row = blockIdx.x*16 + 4q+r.
__global__ __launch_bounds__(512) void yx_kernel(
    const short* __restrict__ Xb16, const short* __restrict__ Mb16,
    unsigned short* __restrict__ YXg, int blk0) {
  const int tid = threadIdx.x;
  const int w = tid >> 6, lane = tid & 63;
  const int nl = lane & 15, q = lane >> 4;
  const int bid = blockIdx.x + blk0;
  const int b = bid >> 7;
  const int f0 = (bid & 127) * 16;
  const int g0 = 256 * w;

  const short* __restrict__ Xb = Xb16 + (size_t)b * F_ * N_;
  const short* __restrict__ Mb = Mb16 + (size_t)b * F_ * N_;

  const short* Ax = Xb + (size_t)(f0 + nl) * N_ + 8 * q;
  const short* Am = Mb + (size_t)(f0 + nl) * N_ + 8 * q;
  const bf16x8 ax0 = *(const bf16x8*)(Ax);
  const bf16x8 ax1 = *(const bf16x8*)(Ax + 32);
  const bf16x8 am0 = *(const bf16x8*)(Am);
  const bf16x8 am1 = *(const bf16x8*)(Am + 32);

  v4f acc[16];
#pragma unroll
  for (int t = 0; t < 16; ++t) acc[t] = (v4f)(0.f);

#pragma unroll
  for (int t = 0; t < 16; ++t) {
    const short* Bm = Mb + (size_t)(g0 + 16 * t + nl) * N_ + 8 * q;
    const short* Bx = Xb + (size_t)(g0 + 16 * t + nl) * N_ + 8 * q;
    const bf16x8 bm0 = *(const bf16x8*)(Bm);
    const bf16x8 bm1 = *(const bf16x8*)(Bm + 32);
    const bf16x8 bx0 = *(const bf16x8*)(Bx);
    const bf16x8 bx1 = *(const bf16x8*)(Bx + 32);
    acc[t] = __builtin_amdgcn_mfma_f32_16x16x32_bf16(ax0, bm0, acc[t], 0, 0, 0);
    acc[t] = __builtin_amdgcn_mfma_f32_16x16x32_bf16(ax1, bm1, acc[t], 0, 0, 0);
    acc[t] = __builtin_amdgcn_mfma_f32_16x16x32_bf16(am0, bx0, acc[t], 0, 0, 0);
    acc[t] = __builtin_amdgcn_mfma_f32_16x16x32_bf16(am1, bx1, acc[t], 0, 0, 0);
  }

  // C-frag (col=lane&15, row=q*4+r) -> global bf16 keys, chunk-local rows
  unsigned short* out =
      YXg + (size_t)(blockIdx.x * 16 + 4 * q) * F_;
#pragma unroll
  for (int t = 0; t < 16; ++t) {
    const int col = g0 + 16 * t + nl;
#pragma unroll
    for (int r = 0; r < 4; ++r)
      out[(size_t)r * F_ + col] = (unsigned short)f2bf(acc[t][r]);
  }
}

// K2b: selection at high occupancy. Block = 256 threads (4 waves),
// ONE row per wave, 4 KB LDS (per-wave 256-bin histogram), no AGPRs.
// Radix starts from the full 16-bit range (lo=0, R=0xFFFF): exactly 2
// passes, provably the same T/tie_need as the min/max-narrowed variant.
__global__ __launch_bounds__(256) void select_kernel(
    const unsigned short* __restrict__ YXg, float* __restrict__ C,
    int rowbase) {
  __shared__ unsigned histS[4 * 256];       // 4 KB
  const int tid = threadIdx.x;
  const int w = tid >> 6, lane = tid & 63;
  const int lrow = blockIdx.x * 4 + w;      // chunk-local row
  const int grow = rowbase + lrow;          // global row in [0, B*F)
  const int frow = grow & (F_ - 1);         // row index within the batch

  const uint4* rp = (const uint4*)(YXg + (size_t)lrow * F_);
  unsigned* wh = &histS[w << 8];

  // single global pass: pack 2x16-bit total-order keys per dword
  unsigned pk[16];
#pragma unroll
  for (int j = 0; j < 4; ++j) {
    const uint4 tt = rp[lane + 64 * j];
    const unsigned wds[4] = {tt.x, tt.y, tt.z, tt.w};
#pragma unroll
    for (int c = 0; c < 4; ++c) pk[4 * j + c] = ordpair(wds[c]);
  }

  // exact 1024-th largest: fixed 2-pass radix on 16-bit ord keys
  unsigned lo = 0, R = 0xFFFFu, krem = K_;
  unsigned T, tie_need;
  for (;;) {
    const int pos = 31 - __builtin_clz(R);
    const int sh = (pos > 7) ? (pos - 7) : 0;
#pragma unroll
    for (int i = 0; i < 4; ++i) wh[lane + 64 * i] = 0u;
    __builtin_amdgcn_wave_barrier();
#pragma unroll
    for (int c = 0; c < 16; ++c) {
      const unsigned o = pk[c];
      const unsigned d0 = (o & 0xFFFFu) - lo;
      const unsigned d1 = (o >> 16) - lo;
      if (d0 <= R) atomicAdd(&wh[d0 >> sh], 1u);
      if (d1 <= R) atomicAdd(&wh[d1 >> sh], 1u);
    }
    __builtin_amdgcn_wave_barrier();
    unsigned h[4];
#pragma unroll
    for (int i = 0; i < 4; ++i) h[i] = wh[4 * lane + i];
    unsigned s3 = h[3], s2 = h[2] + s3, s1 = h[1] + s2, s0 = h[0] + s1;
    unsigned tot = s0;
#pragma unroll
    for (int off = 1; off < 64; off <<= 1) {
      const unsigned v = __shfl_down(tot, off, 64);
      if (lane + off < 64) tot += v;
    }
    const unsigned above = tot - s0;  // count with bucket >= 4*(lane+1)
    const unsigned S[4] = {above + s0, above + s1, above + s2, above + s3};
    unsigned packed = 0;
    bool found = false;
#pragma unroll
    for (int i = 0; i < 4; ++i) {
      const unsigned Sip1 = S[i] - h[i];
      if (S[i] >= krem && Sip1 < krem) {
        packed = ((unsigned)(4 * lane + i) << 16) | Sip1;
        found = true;
      }
    }
    const unsigned long long bm = __ballot(found);
    const int winner = __ffsll(bm) - 1;
    packed = (unsigned)__shfl((int)packed, winner, 64);
    const unsigned D = packed >> 16;
    krem -= (packed & 0xFFFFu);
    if (sh == 0) { T = lo + D; tie_need = krem; break; }
    lo += (D << sh);
    R = (1u << sh) - 1u;
  }

  // final pass (register keys): sums over key > T, tie counts per group
  float vs = 0.f, ws = 0.f;
  unsigned cnt[4];
#pragma unroll
  for (int j = 0; j < 4; ++j) {
    cnt[j] = 0;
#pragma unroll
    for (int c = 0; c < 4; ++c) {
      const unsigned o = pk[4 * j + c];
      const unsigned oo[2] = {o & 0xFFFFu, o >> 16};
#pragma unroll
      for (int i = 0; i < 2; ++i) {
        const int g = 512 * j + 8 * lane + 2 * c + i;
        if (oo[i] > T) {
          const float pv = __expf(bf2f(ord2u16(oo[i])));
          vs += pv; ws += pv * fabsf((float)(g - frow));
        } else if (oo[i] == T) cnt[j]++;
      }
    }
  }
  const float ptie = __expf(bf2f(ord2u16(T)));

  // index-ordered tie selection: 16-bit-field scans (2 fields/word, <=512)
  unsigned pA = cnt[0] | (cnt[1] << 16), pB = cnt[2] | (cnt[3] << 16);
  unsigned iA = pA, iB = pB;
#pragma unroll
  for (int off = 1; off < 64; off <<= 1) {
    const unsigned vA = __shfl_up(iA, off, 64);
    const unsigned vB = __shfl_up(iB, off, 64);
    if (lane >= off) { iA += vA; iB += vB; }
  }
  const unsigned eA = iA - pA, eB = iB - pB;
  const unsigned tA = (unsigned)__shfl((int)iA, 63, 64);
  const unsigned tB = (unsigned)__shfl((int)iB, 63, 64);
  unsigned G[4];
  G[0] = 0;
  G[1] = G[0] + (tA & 0xFFFFu);
  G[2] = G[1] + (tA >> 16);
  G[3] = G[2] + (tB & 0xFFFFu);
#pragma unroll
  for (int j = 0; j < 4; ++j) {
    if (cnt[j]) {
      const unsigned off = (j < 2) ? ((eA >> (16 * j)) & 0xFFFFu)
                                   : ((eB >> (16 * (j - 2))) & 0xFFFFu);
      unsigned cc = 0;
#pragma unroll
      for (int c = 0; c < 4; ++c) {
        const unsigned o = pk[4 * j + c];
        const unsigned oo[2] = {o & 0xFFFFu, o >> 16};
#pragma unroll
        for (int i = 0; i < 2; ++i) {
          if (oo[i] == T) {
            if (G[j] + off + cc < tie_need) {
              const int g = 512 * j + 8 * lane + 2 * c + i;
              vs += ptie; ws += ptie * fabsf((float)(g - frow));
            }
            cc++;
          }
        }
      }
    }
  }

  vs = wave_sum(vs); ws = wave_sum(ws);
  if (lane == 0)
    C[grow] = (ws / vs) * (1.f / (float)K_);
}

// Fused fallback (verified round-10 kernel) — used only if ws too small.
__global__ __launch_bounds__(512)
__attribute__((amdgpu_waves_per_eu(4, 4)))
void rows_kernel(
    const short* __restrict__ Xb16, const short* __restrict__ Mb16,
    float* __restrict__ C) {
  __shared__ unsigned short yxu[16 * YP];
  __shared__ unsigned histS[8 * 256];

  const int tid = threadIdx.x;
  const int w = tid >> 6, lane = tid & 63;
  const int nl = lane & 15, q = lane >> 4;
  const int b = blockIdx.x >> 7;
  const int f0 = (blockIdx.x & 127) * 16;
  const int g0 = 256 * w;

  const short* __restrict__ Xb = Xb16 + (size_t)b * F_ * N_;
  const short* __restrict__ Mb = Mb16 + (size_t)b * F_ * N_;

  const short* Ax = Xb + (size_t)(f0 + nl) * N_ + 8 * q;
  const short* Am = Mb + (size_t)(f0 + nl) * N_ + 8 * q;
  const bf16x8 ax0 = *(const bf16x8*)(Ax);
  const bf16x8 ax1 = *(const bf16x8*)(Ax + 32);
  const bf16x8 am0 = *(const bf16x8*)(Am);
  const bf16x8 am1 = *(const bf16x8*)(Am + 32);

  v4f acc[16];
#pragma unroll
  for (int t = 0; t < 16; ++t) acc[t] = (v4f)(0.f);

#pragma unroll
  for (int t = 0; t < 16; ++t) {
    const short* Bm = Mb + (size_t)(g0 + 16 * t + nl) * N_ + 8 * q;
    const short* Bx = Xb + (size_t)(g0 + 16 * t + nl) * N_ + 8 * q;
    const bf16x8 bm0 = *(const bf16x8*)(Bm);
    const bf16x8 bm1 = *(const bf16x8*)(Bm + 32);
    const bf16x8 bx0 = *(const bf16x8*)(Bx);
    const bf16x8 bx1 = *(const bf16x8*)(Bx + 32);
    acc[t] = __builtin_amdgcn_mfma_f32_16x16x32_bf16(ax0, bm0, acc[t], 0, 0, 0);
    acc[t] = __builtin_amdgcn_mfma_f32_16x16x32_bf16(ax1, bm1, acc[t], 0, 0, 0);
    acc[t] = __builtin_amdgcn_mfma_f32_16x16x32_bf16(am0, bx0, acc[t], 0, 0, 0);
    acc[t] = __builtin_amdgcn_mfma_f32_16x16x32_bf16(am1, bx1, acc[t], 0, 0, 0);
  }

#pragma unroll
  for (int t = 0; t < 16; ++t) {
    const int col = g0 + 16 * t + nl;
#pragma unroll
    for (int r = 0; r < 4; ++r)
      yxu[(4 * q + r) * YP + col] = (unsigned short)f2bf(acc[t][r]);
  }
  __syncthreads();

  unsigned* wh = &histS[w << 8];
#pragma unroll 1
  for (int r4 = 0; r4 < 2; ++r4) {
    const int row = 2 * w + r4;
    const int frow = f0 + row;
    const uint4* rp = (const uint4*)(yxu + row * YP);

    unsigned pk[16];
    unsigned kmin = 0xFFFFFFFFu, kmax = 0u;
#pragma unroll
    for (int j = 0; j < 4; ++j) {
      const uint4 tt = rp[lane + 64 * j];
      const unsigned wds[4] = {tt.x, tt.y, tt.z, tt.w};
#pragma unroll
      for (int c = 0; c < 4; ++c) {
        const unsigned o = ordpair(wds[c]);
        pk[4 * j + c] = o;
        const unsigned o0 = o & 0xFFFFu, o1 = o >> 16;
        kmin = min(kmin, min(o0, o1));
        kmax = max(kmax, max(o0, o1));
      }
    }
#pragma unroll
    for (int off = 32; off > 0; off >>= 1) {
      kmin = min(kmin, (unsigned)__shfl_down((int)kmin, off, 64));
      kmax = max(kmax, (unsigned)__shfl_down((int)kmax, off, 64));
    }
    kmin = (unsigned)__shfl((int)kmin, 0, 64);
    kmax = (unsigned)__shfl((int)kmax, 0, 64);

    unsigned lo = kmin, R = kmax - kmin, krem = K_;
    unsigned T, tie_need;
    if (R == 0) {
      T = lo; tie_need = krem;
    } else {
      for (;;) {
        const int pos = 31 - __builtin_clz(R);
        const int sh = (pos > 7) ? (pos - 7) : 0;
#pragma unroll
        for (int i = 0; i < 4; ++i) wh[lane + 64 * i] = 0u;
        __builtin_amdgcn_wave_barrier();
#pragma unroll
        for (int c = 0; c < 16; ++c) {
          const unsigned o = pk[c];
          const unsigned d0 = (o & 0xFFFFu) - lo;
          const unsigned d1 = (o >> 16) - lo;
          if (d0 <= R) atomicAdd(&wh[d0 >> sh], 1u);
          if (d1 <= R) atomicAdd(&wh[d1 >> sh], 1u);
        }
        __builtin_amdgcn_wave_barrier();
        unsigned h[4];
#pragma unroll
        for (int i = 0; i < 4; ++i) h[i] = wh[4 * lane + i];
        unsigned s3 = h[3], s2 = h[2] + s3, s1 = h[1] + s2, s0 = h[0] + s1;
        unsigned tot = s0;
#pragma unroll
        for (int off = 1; off < 64; off <<= 1) {
          const unsigned v = __shfl_down(tot, off, 64);
          if (lane + off < 64) tot += v;
        }
        const unsigned above = tot - s0;
        const unsigned S[4] = {above + s0, above + s1, above + s2, above + s3};
        unsigned packed = 0;
        bool found = false;
#pragma unroll
        for (int i = 0; i < 4; ++i) {
          const unsigned Sip1 = S[i] - h[i];
          if (S[i] >= krem && Sip1 < krem) {
            packed = ((unsigned)(4 * lane + i) << 16) | Sip1;
            found = true;
          }
        }
        const unsigned long long bm = __ballot(found);
        const int winner = __ffsll(bm) - 1;
        packed = (unsigned)__shfl((int)packed, winner, 64);
        const unsigned D = packed >> 16;
        krem -= (packed & 0xFFFFu);
        if (sh == 0) { T = lo + D; tie_need = krem; break; }
        lo += (D << sh);
        R = (1u << sh) - 1u;
      }
    }

    float vs = 0.f, ws = 0.f;
    unsigned cnt[4];
#pragma unroll
    for (int j = 0; j < 4; ++j) {
      cnt[j] = 0;
#pragma unroll
      for (int c = 0; c < 4; ++c) {
        const unsigned o = pk[4 * j + c];
        const unsigned oo[2] = {o & 0xFFFFu, o >> 16};
#pragma unroll
        for (int i = 0; i < 2; ++i) {
          const int g = 512 * j + 8 * lane + 2 * c + i;
          if (oo[i] > T) {
            const float pv = __expf(bf2f(ord2u16(oo[i])));
            vs += pv; ws += pv * fabsf((float)(g - frow));
          } else if (oo[i] == T) cnt[j]++;
        }
      }
    }
    const float ptie = __expf(bf2f(ord2u16(T)));

    unsigned pA = cnt[0] | (cnt[1] << 16), pB = cnt[2] | (cnt[3] << 16);
    unsigned iA = pA, iB = pB;
#pragma unroll
    for (int off = 1; off < 64; off <<= 1) {
      const unsigned vA = __shfl_up(iA, off, 64);
      const unsigned vB = __shfl_up(iB, off, 64);
      if (lane >= off) { iA += vA; iB += vB; }
    }
    const unsigned eA = iA - pA, eB = iB - pB;
    const unsigned tA = (unsigned)__shfl((int)iA, 63, 64);
    const unsigned tB = (unsigned)__shfl((int)iB, 63, 64);
    unsigned G[4];
    G[0] = 0;
    G[1] = G[0] + (tA & 0xFFFFu);
    G[2] = G[1] + (tA >> 16);
    G[3] = G[2] + (tB & 0xFFFFu);
#pragma unroll
    for (int j = 0; j < 4; ++j) {
      if (cnt[j]) {
        const unsigned off = (j < 2) ? ((eA >> (16 * j)) & 0xFFFFu)
                                     : ((eB >> (16 * (j - 2))) & 0xFFFFu);
        unsigned cc = 0;
#pragma unroll
        for (int c = 0; c < 4; ++c) {
          const unsigned o = pk[4 * j + c];
          const unsigned oo[2] = {o & 0xFFFFu, o >> 16};
#pragma unroll
          for (int i = 0; i < 2; ++i) {
            if (oo[i] == T) {
              if (G[j] + off + cc < tie_need) {
                const int g = 512 * j + 8 * lane + 2 * c + i;
                vs += ptie; ws += ptie * fabsf((float)(g - frow));
              }
              cc++;
            }
          }
        }
      }
    }

    vs = wave_sum(vs); ws = wave_sum(ws);
    if (lane == 0)
      C[(size_t)b * F_ + frow] = (ws / vs) * (1.f / (float)K_);
  }
}

// K3: cmin = min(C); out = mean(exp(-C + cmin - 1e-6)) (unchanged).
__global__ __launch_bounds__(1024) void final_kernel(
    const float* __restrict__ C, unsigned* __restrict__ out) {
  __shared__ float red[16];
  const int tid = threadIdx.x;
  const int wave = tid >> 6, lane = tid & 63;
  float v[32];
  float mn = 3.4e38f;
#pragma unroll
  for (int i = 0; i < 32; ++i) {
    v[i] = C[tid + 1024 * i];
    mn = fminf(mn, v[i]);
  }
  mn = -wave_max(-mn);
  if (lane == 0) red[wave] = mn;
  __syncthreads();
  float cmin = red[0];
  for (int w = 1; w < 16; ++w) cmin = fminf(cmin, red[w]);
  __syncthreads();
  float s = 0.f;
#pragma unroll
  for (int i = 0; i < 32; ++i) s += expf(cmin - v[i] - 1e-6f);
  s = wave_sum(s);
  if (lane == 0) red[wave] = s;
  __syncthreads();
  if (tid == 0) {
    float tot = 0.f;
    for (int w = 0; w < 16; ++w) tot += red[w];
    const float res = tot * (1.f / 32768.f);
    const __hip_bfloat16 hb = __float2bfloat16(res);
    const unsigned short u = *(const unsigned short*)&hb;
    out[0] = ((unsigned)u << 16) | (unsigned)u;
  }
}

extern "C" void kernel_launch(void* const* d_in, const int* in_sizes, int n_in,
                              void* d_out, int out_size, void* d_ws, size_t ws_size,
                              hipStream_t stream) {
  const float* X = (const float*)d_in[0];
  const float* M = (const float*)d_in[1];
  short* Xb16 = (short*)d_ws;                          // 4 MB
  short* Mb16 = Xb16 + (size_t)B_ * F_ * N_;           // 4 MB
  float* C = (float*)(Mb16 + (size_t)B_ * F_ * N_);    // 128 KB
  float* P = C + (size_t)B_ * F_;                      // 256 KB
  unsigned short* YXg = (unsigned short*)(P + (size_t)B_ * N_ * 4 * 16);
  const size_t base_bytes = (size_t)(8 * 1024 * 1024) + 128 * 1024 + 512 * 1024 + 64 * 1024;
  // exact base: 4M+4M Xb/Mb shorts + 128K C + 256K P = 8,781,824; pad a bit.

  stats_kernel<<<dim3(B_ * 16), dim3(256), 0, stream>>>(X, M, P);
  normbf_kernel<<<dim3(B_ * 16), dim3(256), 0, stream>>>(X, M, P, Xb16, Mb16);

  const int total_blk = B_ * (F_ / 16);                // 2048 16-row blocks
  const size_t blk_bytes = (size_t)16 * F_ * 2;        // 64 KB per 16-row block
  int cb = 0;
  if (ws_size > base_bytes + blk_bytes)
    cb = (int)((ws_size - base_bytes) / blk_bytes);
  if (cb < 1) {
    rows_kernel<<<dim3(total_blk), dim3(512), 0, stream>>>(Xb16, Mb16, C);
  } else {
    if (cb > total_blk) cb = total_blk;
    for (int s = 0; s < total_blk; s += cb) {
      const int nb = (s + cb <= total_blk) ? cb : (total_blk - s);
      yx_kernel<<<dim3(nb), dim3(512), 0, stream>>>(Xb16, Mb16, YXg, s);
      select_kernel<<<dim3(nb * 4), dim3(256), 0, stream>>>(YXg, C, s * 16);
    }
  }
  final_kernel<<<dim3(1), dim3(1024), 0, stream>>>(C, (unsigned*)d_out);
}

// Round 5
// 297.326 us; speedup vs baseline: 1.0426x; 1.0426x over previous
//
#include <hip/hip_runtime.h>
#include <hip/hip_bf16.h>
#include <math.h>

// Problem constants (fixed shapes from setup_inputs)
#define B_   16
#define F_   2048
#define N_   64
#define K_   1024   // F/2
#define YP   2056   // padded LDS row stride (ushorts) — fused fallback only

typedef short bf16x8 __attribute__((ext_vector_type(8)));  // 8 bf16 = 4 VGPR
typedef float v4f    __attribute__((ext_vector_type(4)));  // MFMA C/D frag

__device__ __forceinline__ float wave_sum(float v) {
#pragma unroll
  for (int off = 32; off > 0; off >>= 1) v += __shfl_down(v, off, 64);
  return v;
}
__device__ __forceinline__ float wave_max(float v) {
#pragma unroll
  for (int off = 32; off > 0; off >>= 1) v = fmaxf(v, __shfl_down(v, off, 64));
  return v;
}
// butterfly sum: ALL lanes receive the total (no broadcast needed)
__device__ __forceinline__ unsigned wave_sum_bcast(unsigned v) {
#pragma unroll
  for (int off = 32; off > 0; off >>= 1)
    v += (unsigned)__shfl_xor((int)v, off, 64);
  return v;
}

// fp32 -> bf16 bits, round-to-nearest-even (finite inputs only)
__device__ __forceinline__ unsigned f2bf(float x) {
  const unsigned u = __float_as_uint(x);
  return (u + 0x7FFFu + ((u >> 16) & 1u)) >> 16;
}
__device__ __forceinline__ float bf2f(unsigned us) {
  return __uint_as_float(us << 16);
}
// 16-bit total-order inverse: ord -> bf16 bits
__device__ __forceinline__ unsigned ord2u16(unsigned T) {
  return (T & 0x8000u) ? (T ^ 0x8000u) : (T ^ 0xFFFFu);
}
// packed pair of ord16 keys from a dword of 2 bf16 values
__device__ __forceinline__ unsigned ordpair(unsigned wd) {
  return wd ^ (0x80008000u | (((wd & 0x80008000u) >> 15) * 0x7FFFu));
}

// K0: per-(b,n) feature stats, ATOMIC-FREE (unchanged, verified).
__global__ __launch_bounds__(256) void stats_kernel(
    const float* __restrict__ X, const float* __restrict__ M,
    float* __restrict__ P) {
  __shared__ float red[4][N_][4];   // [fi][n][word], 4 KB
  const int tid = threadIdx.x;
  const int b = blockIdx.x >> 4;
  const int fb = blockIdx.x & 15;
  const int f0 = fb * 128;
  const int fi = tid >> 6, n = tid & 63;
  float sx = 0.f, sxx = 0.f, sm = 0.f, smm = 0.f;
#pragma unroll 4
  for (int j = 0; j < 32; ++j) {
    const int f = f0 + fi + 4 * j;
    const size_t gi = ((size_t)b * F_ + f) * N_ + n;
    const float x = X[gi];
    const float m = M[gi];
    sx += x; sxx += x * x; sm += m; smm += m * m;
  }
  red[fi][n][0] = sx; red[fi][n][1] = sxx;
  red[fi][n][2] = sm; red[fi][n][3] = smm;
  __syncthreads();
  const int wn = tid & 63, word = tid >> 6;
  const float s = red[0][wn][word] + red[1][wn][word] +
                  red[2][wn][word] + red[3][wn][word];
  P[(((size_t)b * N_ + wn) * 4 + word) * 16 + fb] = s;
}

// K1: center + L2-normalize per (b,n); write bf16 (unchanged, verified).
__global__ __launch_bounds__(256) void normbf_kernel(
    const float* __restrict__ X, const float* __restrict__ M,
    const float* __restrict__ P,
    short* __restrict__ Xb16, short* __restrict__ Mb16) {
  const int tid = threadIdx.x;
  const int b = blockIdx.x >> 4;
  const int f0 = (blockIdx.x & 15) * 128;
  const int n = tid & 63;
  const float* base = P + (((size_t)b * N_ + n) * 4) * 16;
  float acc4[4];
#pragma unroll
  for (int wj = 0; wj < 4; ++wj) {
    float s = 0.f;
#pragma unroll
    for (int i = 0; i < 16; ++i) s += base[16 * wj + i];
    acc4[wj] = s;
  }
  const float sx = acc4[0], sxx = acc4[1], sm = acc4[2], smm = acc4[3];
  const float mux = sx * (1.f / F_), mum = sm * (1.f / F_);
  const float rx = 1.f / (sqrtf(fmaxf(sxx - (float)F_ * mux * mux, 0.f)) + 1e-10f);
  const float rm = 1.f / (sqrtf(fmaxf(smm - (float)F_ * mum * mum, 0.f)) + 1e-10f);
#pragma unroll 4
  for (int jj = 0; jj < 32; ++jj) {
    const int f = f0 + (tid >> 6) + 4 * jj;
    const size_t gi = ((size_t)b * F_ + f) * N_ + n;
    Xb16[gi] = (short)f2bf((X[gi] - mux) * rx);
    Mb16[gi] = (short)f2bf((M[gi] - mum) * rm);
  }
}

// K2a (round-4): GEMM with COLUMN-SHARED blocks. Block = 128 rows x 256
// cols: all 8 waves read the SAME B-frags (256-col range), cutting B
// traffic per block 512KB -> 64KB (L1/MSHR merge across waves). Inner
// loop identical to the verified kernel; only the f0/g0 mapping changed.
// Stores deliberately unchanged (2B scattered) to isolate this effect.
__global__ __launch_bounds__(512) void yx_kernel(
    const short* __restrict__ Xb16, const short* __restrict__ Mb16,
    unsigned short* __restrict__ YXg) {
  const int tid = threadIdx.x;
  const int w = tid >> 6, lane = tid & 63;
  const int nl = lane & 15, q = lane >> 4;
  const int bid = blockIdx.x;
  const int b = bid >> 7;                   // 128 blocks per batch
  const int rgrp = (bid >> 3) & 15;         // 16 row-groups of 128 rows
  const int cgrp = bid & 7;                 // 8 col-groups of 256 cols
  const int f0 = rgrp * 128 + 16 * w;       // this wave's 16-row base
  const int g0 = cgrp * 256;                // block-shared 256-col base

  const short* __restrict__ Xb = Xb16 + (size_t)b * F_ * N_;
  const short* __restrict__ Mb = Mb16 + (size_t)b * F_ * N_;

  // A-frags (rows f0..f0+15): A[m=nl][k=32*s+8*q+j]
  const short* Ax = Xb + (size_t)(f0 + nl) * N_ + 8 * q;
  const short* Am = Mb + (size_t)(f0 + nl) * N_ + 8 * q;
  const bf16x8 ax0 = *(const bf16x8*)(Ax);
  const bf16x8 ax1 = *(const bf16x8*)(Ax + 32);
  const bf16x8 am0 = *(const bf16x8*)(Am);
  const bf16x8 am1 = *(const bf16x8*)(Am + 32);

  v4f acc[16];
#pragma unroll
  for (int t = 0; t < 16; ++t) acc[t] = (v4f)(0.f);

#pragma unroll
  for (int t = 0; t < 16; ++t) {
    const short* Bm = Mb + (size_t)(g0 + 16 * t + nl) * N_ + 8 * q;
    const short* Bx = Xb + (size_t)(g0 + 16 * t + nl) * N_ + 8 * q;
    const bf16x8 bm0 = *(const bf16x8*)(Bm);
    const bf16x8 bm1 = *(const bf16x8*)(Bm + 32);
    const bf16x8 bx0 = *(const bf16x8*)(Bx);
    const bf16x8 bx1 = *(const bf16x8*)(Bx + 32);
    acc[t] = __builtin_amdgcn_mfma_f32_16x16x32_bf16(ax0, bm0, acc[t], 0, 0, 0);
    acc[t] = __builtin_amdgcn_mfma_f32_16x16x32_bf16(ax1, bm1, acc[t], 0, 0, 0);
    acc[t] = __builtin_amdgcn_mfma_f32_16x16x32_bf16(am0, bx0, acc[t], 0, 0, 0);
    acc[t] = __builtin_amdgcn_mfma_f32_16x16x32_bf16(am1, bx1, acc[t], 0, 0, 0);
  }

  // C-frag (col=lane&15, row=q*4+r) -> global bf16 keys, ABSOLUTE rows
  unsigned short* out = YXg + ((size_t)b * F_ + f0 + 4 * q) * F_;
#pragma unroll
  for (int t = 0; t < 16; ++t) {
    const int col = g0 + 16 * t + nl;
#pragma unroll
    for (int r = 0; r < 4; ++r)
      out[(size_t)r * F_ + col] = (unsigned short)f2bf(acc[t][r]);
  }
}

// K2b (round-4): selection with NO LDS and NO atomics. One row per wave.
// T found by 16-step binary search on the ord16 space: maximal T with
// count(key >= T) >= K. tie_need = K - (count(>=T) - count(==T)), where
// count(==T) falls out of the existing tie-scan totals. Final/tie passes
// identical to the verified kernel.
__global__ __launch_bounds__(256) void select_kernel(
    const unsigned short* __restrict__ YXg, float* __restrict__ C) {
  const int tid = threadIdx.x;
  const int w = tid >> 6, lane = tid & 63;
  const int grow = blockIdx.x * 4 + w;      // absolute row in [0, B*F)
  const int frow = grow & (F_ - 1);         // row index within the batch

  const uint4* rp = (const uint4*)(YXg + (size_t)grow * F_);

  // single global pass: pack 2x16-bit total-order keys per dword
  unsigned pk[16];
#pragma unroll
  for (int j = 0; j < 4; ++j) {
    const uint4 tt = rp[lane + 64 * j];
    const unsigned wds[4] = {tt.x, tt.y, tt.z, tt.w};
#pragma unroll
    for (int c = 0; c < 4; ++c) pk[4 * j + c] = ordpair(wds[c]);
  }

  // binary search for T (maximal with count(>=T) >= K); nge = count(>=T)
  unsigned T = 0, nge = 2048;               // cnt_ge(0) == 2048 always
#pragma unroll 1
  for (int bit = 15; bit >= 0; --bit) {
    const unsigned cand = T | (1u << bit);
    unsigned cnt = 0;
#pragma unroll
    for (int c = 0; c < 16; ++c) {
      const unsigned o = pk[c];
      cnt += ((o & 0xFFFFu) >= cand) ? 1u : 0u;
      cnt += ((o >> 16) >= cand) ? 1u : 0u;
    }
    cnt = wave_sum_bcast(cnt);
    if (cnt >= K_) { T = cand; nge = cnt; }
  }

  // final pass (register keys): sums over key > T, tie counts per group
  float vs = 0.f, ws = 0.f;
  unsigned cnt[4];
#pragma unroll
  for (int j = 0; j < 4; ++j) {
    cnt[j] = 0;
#pragma unroll
    for (int c = 0; c < 4; ++c) {
      const unsigned o = pk[4 * j + c];
      const unsigned oo[2] = {o & 0xFFFFu, o >> 16};
#pragma unroll
      for (int i = 0; i < 2; ++i) {
        const int g = 512 * j + 8 * lane + 2 * c + i;
        if (oo[i] > T) {
          const float pv = __expf(bf2f(ord2u16(oo[i])));
          vs += pv; ws += pv * fabsf((float)(g - frow));
        } else if (oo[i] == T) cnt[j]++;
      }
    }
  }
  const float ptie = __expf(bf2f(ord2u16(T)));

  // index-ordered tie selection: 16-bit-field scans (2 fields/word, <=512)
  unsigned pA = cnt[0] | (cnt[1] << 16), pB = cnt[2] | (cnt[3] << 16);
  unsigned iA = pA, iB = pB;
#pragma unroll
  for (int off = 1; off < 64; off <<= 1) {
    const unsigned vA = __shfl_up(iA, off, 64);
    const unsigned vB = __shfl_up(iB, off, 64);
    if (lane >= off) { iA += vA; iB += vB; }
  }
  const unsigned eA = iA - pA, eB = iB - pB;
  const unsigned tA = (unsigned)__shfl((int)iA, 63, 64);
  const unsigned tB = (unsigned)__shfl((int)iB, 63, 64);
  unsigned G[4];
  G[0] = 0;
  G[1] = G[0] + (tA & 0xFFFFu);
  G[2] = G[1] + (tA >> 16);
  G[3] = G[2] + (tB & 0xFFFFu);
  const unsigned total_ties = G[3] + (tB >> 16);
  const unsigned tie_need = K_ - (nge - total_ties);  // == K - count(>T)
#pragma unroll
  for (int j = 0; j < 4; ++j) {
    if (cnt[j]) {
      const unsigned off = (j < 2) ? ((eA >> (16 * j)) & 0xFFFFu)
                                   : ((eB >> (16 * (j - 2))) & 0xFFFFu);
      unsigned cc = 0;
#pragma unroll
      for (int c = 0; c < 4; ++c) {
        const unsigned o = pk[4 * j + c];
        const unsigned oo[2] = {o & 0xFFFFu, o >> 16};
#pragma unroll
        for (int i = 0; i < 2; ++i) {
          if (oo[i] == T) {
            if (G[j] + off + cc < tie_need) {
              const int g = 512 * j + 8 * lane + 2 * c + i;
              vs += ptie; ws += ptie * fabsf((float)(g - frow));
            }
            cc++;
          }
        }
      }
    }
  }

  vs = wave_sum(vs); ws = wave_sum(ws);
  if (lane == 0)
    C[grow] = (ws / vs) * (1.f / (float)K_);
}

// Fused fallback (verified round-10 kernel) — used only if ws too small.
__global__ __launch_bounds__(512)
__attribute__((amdgpu_waves_per_eu(4, 4)))
void rows_kernel(
    const short* __restrict__ Xb16, const short* __restrict__ Mb16,
    float* __restrict__ C) {
  __shared__ unsigned short yxu[16 * YP];
  __shared__ unsigned histS[8 * 256];

  const int tid = threadIdx.x;
  const int w = tid >> 6, lane = tid & 63;
  const int nl = lane & 15, q = lane >> 4;
  const int b = blockIdx.x >> 7;
  const int f0 = (blockIdx.x & 127) * 16;
  const int g0 = 256 * w;

  const short* __restrict__ Xb = Xb16 + (size_t)b * F_ * N_;
  const short* __restrict__ Mb = Mb16 + (size_t)b * F_ * N_;

  const short* Ax = Xb + (size_t)(f0 + nl) * N_ + 8 * q;
  const short* Am = Mb + (size_t)(f0 + nl) * N_ + 8 * q;
  const bf16x8 ax0 = *(const bf16x8*)(Ax);
  const bf16x8 ax1 = *(const bf16x8*)(Ax + 32);
  const bf16x8 am0 = *(const bf16x8*)(Am);
  const bf16x8 am1 = *(const bf16x8*)(Am + 32);

  v4f acc[16];
#pragma unroll
  for (int t = 0; t < 16; ++t) acc[t] = (v4f)(0.f);

#pragma unroll
  for (int t = 0; t < 16; ++t) {
    const short* Bm = Mb + (size_t)(g0 + 16 * t + nl) * N_ + 8 * q;
    const short* Bx = Xb + (size_t)(g0 + 16 * t + nl) * N_ + 8 * q;
    const bf16x8 bm0 = *(const bf16x8*)(Bm);
    const bf16x8 bm1 = *(const bf16x8*)(Bm + 32);
    const bf16x8 bx0 = *(const bf16x8*)(Bx);
    const bf16x8 bx1 = *(const bf16x8*)(Bx + 32);
    acc[t] = __builtin_amdgcn_mfma_f32_16x16x32_bf16(ax0, bm0, acc[t], 0, 0, 0);
    acc[t] = __builtin_amdgcn_mfma_f32_16x16x32_bf16(ax1, bm1, acc[t], 0, 0, 0);
    acc[t] = __builtin_amdgcn_mfma_f32_16x16x32_bf16(am0, bx0, acc[t], 0, 0, 0);
    acc[t] = __builtin_amdgcn_mfma_f32_16x16x32_bf16(am1, bx1, acc[t], 0, 0, 0);
  }

#pragma unroll
  for (int t = 0; t < 16; ++t) {
    const int col = g0 + 16 * t + nl;
#pragma unroll
    for (int r = 0; r < 4; ++r)
      yxu[(4 * q + r) * YP + col] = (unsigned short)f2bf(acc[t][r]);
  }
  __syncthreads();

  unsigned* wh = &histS[w << 8];
#pragma unroll 1
  for (int r4 = 0; r4 < 2; ++r4) {
    const int row = 2 * w + r4;
    const int frow = f0 + row;
    const uint4* rp = (const uint4*)(yxu + row * YP);

    unsigned pk[16];
    unsigned kmin = 0xFFFFFFFFu, kmax = 0u;
#pragma unroll
    for (int j = 0; j < 4; ++j) {
      const uint4 tt = rp[lane + 64 * j];
      const unsigned wds[4] = {tt.x, tt.y, tt.z, tt.w};
#pragma unroll
      for (int c = 0; c < 4; ++c) {
        const unsigned o = ordpair(wds[c]);
        pk[4 * j + c] = o;
        const unsigned o0 = o & 0xFFFFu, o1 = o >> 16;
        kmin = min(kmin, min(o0, o1));
        kmax = max(kmax, max(o0, o1));
      }
    }
#pragma unroll
    for (int off = 32; off > 0; off >>= 1) {
      kmin = min(kmin, (unsigned)__shfl_down((int)kmin, off, 64));
      kmax = max(kmax, (unsigned)__shfl_down((int)kmax, off, 64));
    }
    kmin = (unsigned)__shfl((int)kmin, 0, 64);
    kmax = (unsigned)__shfl((int)kmax, 0, 64);

    unsigned lo = kmin, R = kmax - kmin, krem = K_;
    unsigned T, tie_need;
    if (R == 0) {
      T = lo; tie_need = krem;
    } else {
      for (;;) {
        const int pos = 31 - __builtin_clz(R);
        const int sh = (pos > 7) ? (pos - 7) : 0;
#pragma unroll
        for (int i = 0; i < 4; ++i) wh[lane + 64 * i] = 0u;
        __builtin_amdgcn_wave_barrier();
#pragma unroll
        for (int c = 0; c < 16; ++c) {
          const unsigned o = pk[c];
          const unsigned d0 = (o & 0xFFFFu) - lo;
          const unsigned d1 = (o >> 16) - lo;
          if (d0 <= R) atomicAdd(&wh[d0 >> sh], 1u);
          if (d1 <= R) atomicAdd(&wh[d1 >> sh], 1u);
        }
        __builtin_amdgcn_wave_barrier();
        unsigned h[4];
#pragma unroll
        for (int i = 0; i < 4; ++i) h[i] = wh[4 * lane + i];
        unsigned s3 = h[3], s2 = h[2] + s3, s1 = h[1] + s2, s0 = h[0] + s1;
        unsigned tot = s0;
#pragma unroll
        for (int off = 1; off < 64; off <<= 1) {
          const unsigned v = __shfl_down(tot, off, 64);
          if (lane + off < 64) tot += v;
        }
        const unsigned above = tot - s0;
        const unsigned S[4] = {above + s0, above + s1, above + s2, above + s3};
        unsigned packed = 0;
        bool found = false;
#pragma unroll
        for (int i = 0; i < 4; ++i) {
          const unsigned Sip1 = S[i] - h[i];
          if (S[i] >= krem && Sip1 < krem) {
            packed = ((unsigned)(4 * lane + i) << 16) | Sip1;
            found = true;
          }
        }
        const unsigned long long bm = __ballot(found);
        const int winner = __ffsll(bm) - 1;
        packed = (unsigned)__shfl((int)packed, winner, 64);
        const unsigned D = packed >> 16;
        krem -= (packed & 0xFFFFu);
        if (sh == 0) { T = lo + D; tie_need = krem; break; }
        lo += (D << sh);
        R = (1u << sh) - 1u;
      }
    }

    float vs = 0.f, ws = 0.f;
    unsigned cnt[4];
#pragma unroll
    for (int j = 0; j < 4; ++j) {
      cnt[j] = 0;
#pragma unroll
      for (int c = 0; c < 4; ++c) {
        const unsigned o = pk[4 * j + c];
        const unsigned oo[2] = {o & 0xFFFFu, o >> 16};
#pragma unroll
        for (int i = 0; i < 2; ++i) {
          const int g = 512 * j + 8 * lane + 2 * c + i;
          if (oo[i] > T) {
            const float pv = __expf(bf2f(ord2u16(oo[i])));
            vs += pv; ws += pv * fabsf((float)(g - frow));
          } else if (oo[i] == T) cnt[j]++;
        }
      }
    }
    const float ptie = __expf(bf2f(ord2u16(T)));

    unsigned pA = cnt[0] | (cnt[1] << 16), pB = cnt[2] | (cnt[3] << 16);
    unsigned iA = pA, iB = pB;
#pragma unroll
    for (int off = 1; off < 64; off <<= 1) {
      const unsigned vA = __shfl_up(iA, off, 64);
      const unsigned vB = __shfl_up(iB, off, 64);
      if (lane >= off) { iA += vA; iB += vB; }
    }
    const unsigned eA = iA - pA, eB = iB - pB;
    const unsigned tA = (unsigned)__shfl((int)iA, 63, 64);
    const unsigned tB = (unsigned)__shfl((int)iB, 63, 64);
    unsigned G[4];
    G[0] = 0;
    G[1] = G[0] + (tA & 0xFFFFu);
    G[2] = G[1] + (tA >> 16);
    G[3] = G[2] + (tB & 0xFFFFu);
#pragma unroll
    for (int j = 0; j < 4; ++j) {
      if (cnt[j]) {
        const unsigned off = (j < 2) ? ((eA >> (16 * j)) & 0xFFFFu)
                                     : ((eB >> (16 * (j - 2))) & 0xFFFFu);
        unsigned cc = 0;
#pragma unroll
        for (int c = 0; c < 4; ++c) {
          const unsigned o = pk[4 * j + c];
          const unsigned oo[2] = {o & 0xFFFFu, o >> 16};
#pragma unroll
          for (int i = 0; i < 2; ++i) {
            if (oo[i] == T) {
              if (G[j] + off + cc < tie_need) {
                const int g = 512 * j + 8 * lane + 2 * c + i;
                vs += ptie; ws += ptie * fabsf((float)(g - frow));
              }
              cc++;
            }
          }
        }
      }
    }

    vs = wave_sum(vs); ws = wave_sum(ws);
    if (lane == 0)
      C[(size_t)b * F_ + frow] = (ws / vs) * (1.f / (float)K_);
  }
}

// K3: cmin = min(C); out = mean(exp(-C + cmin - 1e-6)) (unchanged).
__global__ __launch_bounds__(1024) void final_kernel(
    const float* __restrict__ C, unsigned* __restrict__ out) {
  __shared__ float red[16];
  const int tid = threadIdx.x;
  const int wave = tid >> 6, lane = tid & 63;
  float v[32];
  float mn = 3.4e38f;
#pragma unroll
  for (int i = 0; i < 32; ++i) {
    v[i] = C[tid + 1024 * i];
    mn = fminf(mn, v[i]);
  }
  mn = -wave_max(-mn);
  if (lane == 0) red[wave] = mn;
  __syncthreads();
  float cmin = red[0];
  for (int w = 1; w < 16; ++w) cmin = fminf(cmin, red[w]);
  __syncthreads();
  float s = 0.f;
#pragma unroll
  for (int i = 0; i < 32; ++i) s += expf(cmin - v[i] - 1e-6f);
  s = wave_sum(s);
  if (lane == 0) red[wave] = s;
  __syncthreads();
  if (tid == 0) {
    float tot = 0.f;
    for (int w = 0; w < 16; ++w) tot += red[w];
    const float res = tot * (1.f / 32768.f);
    const __hip_bfloat16 hb = __float2bfloat16(res);
    const unsigned short u = *(const unsigned short*)&hb;
    out[0] = ((unsigned)u << 16) | (unsigned)u;
  }
}

extern "C" void kernel_launch(void* const* d_in, const int* in_sizes, int n_in,
                              void* d_out, int out_size, void* d_ws, size_t ws_size,
                              hipStream_t stream) {
  const float* X = (const float*)d_in[0];
  const float* M = (const float*)d_in[1];
  short* Xb16 = (short*)d_ws;                          // 4 MB
  short* Mb16 = Xb16 + (size_t)B_ * F_ * N_;           // 4 MB
  float* C = (float*)(Mb16 + (size_t)B_ * F_ * N_);    // 128 KB
  float* P = C + (size_t)B_ * F_;                      // 256 KB
  unsigned short* YXg = (unsigned short*)(P + (size_t)B_ * N_ * 4 * 16);
  const size_t base_bytes = (size_t)(8 * 1024 * 1024) + 128 * 1024 + 512 * 1024 + 64 * 1024;
  const size_t need = base_bytes + (size_t)B_ * F_ * F_ * 2;  // + 128 MB YX

  stats_kernel<<<dim3(B_ * 16), dim3(256), 0, stream>>>(X, M, P);
  normbf_kernel<<<dim3(B_ * 16), dim3(256), 0, stream>>>(X, M, P, Xb16, Mb16);

  if (ws_size >= need) {
    yx_kernel<<<dim3(B_ * 128), dim3(512), 0, stream>>>(Xb16, Mb16, YXg);
    select_kernel<<<dim3(B_ * F_ / 4), dim3(256), 0, stream>>>(YXg, C);
  } else {
    rows_kernel<<<dim3(B_ * (F_ / 16)), dim3(512), 0, stream>>>(Xb16, Mb16, C);
  }
  final_kernel<<<dim3(1), dim3(1024), 0, stream>>>(C, (unsigned*)d_out);
}

// Round 6
// 201.001 us; speedup vs baseline: 1.5422x; 1.4792x over previous
//
#include <hip/hip_runtime.h>
#include <hip/hip_bf16.h>
#include <math.h>

// Problem constants (fixed shapes from setup_inputs)
#define B_   16
#define F_   2048
#define N_   64
#define K_   1024   // F/2
#define YP   2056   // padded LDS row stride (ushorts)

typedef short bf16x8 __attribute__((ext_vector_type(8)));  // 8 bf16 = 4 VGPR
typedef float v4f    __attribute__((ext_vector_type(4)));  // MFMA C/D frag

__device__ __forceinline__ float wave_sum(float v) {
#pragma unroll
  for (int off = 32; off > 0; off >>= 1) v += __shfl_down(v, off, 64);
  return v;
}
__device__ __forceinline__ float wave_max(float v) {
#pragma unroll
  for (int off = 32; off > 0; off >>= 1) v = fmaxf(v, __shfl_down(v, off, 64));
  return v;
}

// fp32 -> bf16 bits, round-to-nearest-even (finite inputs only)
__device__ __forceinline__ unsigned f2bf(float x) {
  const unsigned u = __float_as_uint(x);
  return (u + 0x7FFFu + ((u >> 16) & 1u)) >> 16;
}
__device__ __forceinline__ float bf2f(unsigned us) {
  return __uint_as_float(us << 16);
}
// 16-bit total-order inverse: ord -> bf16 bits
__device__ __forceinline__ unsigned ord2u16(unsigned T) {
  return (T & 0x8000u) ? (T ^ 0x8000u) : (T ^ 0xFFFFu);
}
// packed pair of ord16 keys from a dword of 2 bf16 values
__device__ __forceinline__ unsigned ordpair(unsigned wd) {
  return wd ^ (0x80008000u | (((wd & 0x80008000u) >> 15) * 0x7FFFu));
}

// K0: per-(b,n) feature stats, ATOMIC-FREE (unchanged, verified).
__global__ __launch_bounds__(256) void stats_kernel(
    const float* __restrict__ X, const float* __restrict__ M,
    float* __restrict__ P) {
  __shared__ float red[4][N_][4];   // [fi][n][word], 4 KB
  const int tid = threadIdx.x;
  const int b = blockIdx.x >> 4;
  const int fb = blockIdx.x & 15;
  const int f0 = fb * 128;
  const int fi = tid >> 6, n = tid & 63;
  float sx = 0.f, sxx = 0.f, sm = 0.f, smm = 0.f;
#pragma unroll 4
  for (int j = 0; j < 32; ++j) {
    const int f = f0 + fi + 4 * j;
    const size_t gi = ((size_t)b * F_ + f) * N_ + n;
    const float x = X[gi];
    const float m = M[gi];
    sx += x; sxx += x * x; sm += m; smm += m * m;
  }
  red[fi][n][0] = sx; red[fi][n][1] = sxx;
  red[fi][n][2] = sm; red[fi][n][3] = smm;
  __syncthreads();
  const int wn = tid & 63, word = tid >> 6;
  const float s = red[0][wn][word] + red[1][wn][word] +
                  red[2][wn][word] + red[3][wn][word];
  P[(((size_t)b * N_ + wn) * 4 + word) * 16 + fb] = s;
}

// K1 (round-6): center + L2-normalize per (b,n); write bf16 in PACKED MFMA
// fragment order so every GEMM operand load is one contiguous 1KB chunk:
//   chunk (b, t16 = f>>4, s = n>>5) of 512 shorts; within chunk the
//   element for lane l=(q*16+nl) (q=(n>>3)&3, nl=f&15), j=n&7 sits at
//   l*8 + j.  Fragment contents are bit-identical to the old per-lane
//   gather (lane reads X[f0+nl][32s+8q+j]).  Reads stay fully coalesced;
//   stores become 8x16B segments (16 MB total — negligible).
__global__ __launch_bounds__(256) void normbf_kernel(
    const float* __restrict__ X, const float* __restrict__ M,
    const float* __restrict__ P,
    short* __restrict__ Xb16, short* __restrict__ Mb16) {
  const int tid = threadIdx.x;
  const int b = blockIdx.x >> 4;
  const int f0 = (blockIdx.x & 15) * 128;
  const int n = tid & 63;
  const float* base = P + (((size_t)b * N_ + n) * 4) * 16;
  float acc4[4];
#pragma unroll
  for (int wj = 0; wj < 4; ++wj) {
    float s = 0.f;
#pragma unroll
    for (int i = 0; i < 16; ++i) s += base[16 * wj + i];
    acc4[wj] = s;
  }
  const float sx = acc4[0], sxx = acc4[1], sm = acc4[2], smm = acc4[3];
  const float mux = sx * (1.f / F_), mum = sm * (1.f / F_);
  const float rx = 1.f / (sqrtf(fmaxf(sxx - (float)F_ * mux * mux, 0.f)) + 1e-10f);
  const float rm = 1.f / (sqrtf(fmaxf(smm - (float)F_ * mum * mum, 0.f)) + 1e-10f);
  const int s_ = n >> 5, q_ = (n >> 3) & 3, j_ = n & 7;
#pragma unroll 4
  for (int jj = 0; jj < 32; ++jj) {
    const int f = f0 + (tid >> 6) + 4 * jj;
    const size_t gi = ((size_t)b * F_ + f) * N_ + n;
    const int t16 = f >> 4, nl = f & 15;
    const size_t pi = (((size_t)b * 128 + t16) * 2 + s_) * 512 +
                      (q_ * 16 + nl) * 8 + j_;
    Xb16[pi] = (short)f2bf((X[gi] - mux) * rx);
    Mb16[pi] = (short)f2bf((M[gi] - mum) * rm);
  }
}

// K2 (round-6): the VERIFIED fused kernel (round-10 structure, 165 us),
// with operand loads switched to the packed layout: each bf16x8 fragment
// load is now `base + lane*8` — one 1KB fully-coalesced dwordx4 per wave
// instead of 16 discontiguous 64B segments (the round-5 diagnosis: the
// VMEM front-end was segment-bound at ~16 seg/load, ~117 us).
// Everything from the C-frag LDS write onward is byte-identical.
__global__ __launch_bounds__(512)
__attribute__((amdgpu_waves_per_eu(4, 4)))
void rows_kernel(
    const short* __restrict__ Xb16, const short* __restrict__ Mb16,
    float* __restrict__ C) {
  __shared__ unsigned short yxu[16 * YP];   // 65,792 B
  __shared__ unsigned histS[8 * 256];       // 8 KB per-wave histograms

  const int tid = threadIdx.x;
  const int w = tid >> 6, lane = tid & 63;
  const int nl = lane & 15, q = lane >> 4;
  const int b = blockIdx.x >> 7;            // 128 row-blocks per batch
  const int f0 = (blockIdx.x & 127) * 16;
  const int g0 = 256 * w;

  const short* __restrict__ Xb = Xb16 + (size_t)b * F_ * N_;
  const short* __restrict__ Mb = Mb16 + (size_t)b * F_ * N_;

  // A-frags: packed chunk t16 = f0>>4 = blockIdx&127; s=0/1 chunks adjacent
  const short* Axp = Xb + (size_t)(f0 >> 4) * 1024 + lane * 8;
  const short* Amp = Mb + (size_t)(f0 >> 4) * 1024 + lane * 8;
  const bf16x8 ax0 = *(const bf16x8*)(Axp);
  const bf16x8 ax1 = *(const bf16x8*)(Axp + 512);
  const bf16x8 am0 = *(const bf16x8*)(Amp);
  const bf16x8 am1 = *(const bf16x8*)(Amp + 512);

  v4f acc[16];
#pragma unroll
  for (int t = 0; t < 16; ++t) acc[t] = (v4f)(0.f);

#pragma unroll
  for (int t = 0; t < 16; ++t) {
    // B chunk t16 = (g0 + 16t)>>4 = 16w + t
    const short* Bmp = Mb + (size_t)(16 * w + t) * 1024 + lane * 8;
    const short* Bxp = Xb + (size_t)(16 * w + t) * 1024 + lane * 8;
    const bf16x8 bm0 = *(const bf16x8*)(Bmp);
    const bf16x8 bm1 = *(const bf16x8*)(Bmp + 512);
    const bf16x8 bx0 = *(const bf16x8*)(Bxp);
    const bf16x8 bx1 = *(const bf16x8*)(Bxp + 512);
    acc[t] = __builtin_amdgcn_mfma_f32_16x16x32_bf16(ax0, bm0, acc[t], 0, 0, 0);
    acc[t] = __builtin_amdgcn_mfma_f32_16x16x32_bf16(ax1, bm1, acc[t], 0, 0, 0);
    acc[t] = __builtin_amdgcn_mfma_f32_16x16x32_bf16(am0, bx0, acc[t], 0, 0, 0);
    acc[t] = __builtin_amdgcn_mfma_f32_16x16x32_bf16(am1, bx1, acc[t], 0, 0, 0);
  }

  // C-frag (col=lane&15, row=q*4+r, verified m89/m91) -> LDS bf16 keys
#pragma unroll
  for (int t = 0; t < 16; ++t) {
    const int col = g0 + 16 * t + nl;
#pragma unroll
    for (int r = 0; r < 4; ++r)
      yxu[(4 * q + r) * YP + col] = (unsigned short)f2bf(acc[t][r]);
  }
  __syncthreads();

  // ---- per-wave selection: rows 2w, 2w+1; 32 keys/lane (register-cached) --
  unsigned* wh = &histS[w << 8];
#pragma unroll 1
  for (int r4 = 0; r4 < 2; ++r4) {
    const int row = 2 * w + r4;
    const int frow = f0 + row;
    const uint4* rp = (const uint4*)(yxu + row * YP);  // 16B-aligned

    // single LDS pass: pack 2x16-bit total-order keys per dword + range
    unsigned pk[16];
    unsigned kmin = 0xFFFFFFFFu, kmax = 0u;
#pragma unroll
    for (int j = 0; j < 4; ++j) {
      const uint4 tt = rp[lane + 64 * j];
      const unsigned wds[4] = {tt.x, tt.y, tt.z, tt.w};
#pragma unroll
      for (int c = 0; c < 4; ++c) {
        const unsigned o = ordpair(wds[c]);
        pk[4 * j + c] = o;   // packed ord16 pair; uint order == float order
        const unsigned o0 = o & 0xFFFFu, o1 = o >> 16;
        kmin = min(kmin, min(o0, o1));
        kmax = max(kmax, max(o0, o1));
      }
    }
#pragma unroll
    for (int off = 32; off > 0; off >>= 1) {
      kmin = min(kmin, (unsigned)__shfl_down((int)kmin, off, 64));
      kmax = max(kmax, (unsigned)__shfl_down((int)kmax, off, 64));
    }
    kmin = (unsigned)__shfl((int)kmin, 0, 64);
    kmax = (unsigned)__shfl((int)kmax, 0, 64);

    // exact 1024-th largest: floating radix on 16-bit ord keys (<=2 passes)
    unsigned lo = kmin, R = kmax - kmin, krem = K_;
    unsigned T, tie_need;
    if (R == 0) {
      T = lo; tie_need = krem;
    } else {
      for (;;) {
        const int pos = 31 - __builtin_clz(R);
        const int sh = (pos > 7) ? (pos - 7) : 0;
#pragma unroll
        for (int i = 0; i < 4; ++i) wh[lane + 64 * i] = 0u;
        __builtin_amdgcn_wave_barrier();
#pragma unroll
        for (int c = 0; c < 16; ++c) {
          const unsigned o = pk[c];
          const unsigned d0 = (o & 0xFFFFu) - lo;
          const unsigned d1 = (o >> 16) - lo;
          if (d0 <= R) atomicAdd(&wh[d0 >> sh], 1u);
          if (d1 <= R) atomicAdd(&wh[d1 >> sh], 1u);
        }
        __builtin_amdgcn_wave_barrier();
        unsigned h[4];
#pragma unroll
        for (int i = 0; i < 4; ++i) h[i] = wh[4 * lane + i];
        unsigned s3 = h[3], s2 = h[2] + s3, s1 = h[1] + s2, s0 = h[0] + s1;
        unsigned tot = s0;
#pragma unroll
        for (int off = 1; off < 64; off <<= 1) {
          const unsigned v = __shfl_down(tot, off, 64);
          if (lane + off < 64) tot += v;
        }
        const unsigned above = tot - s0;  // count with bucket >= 4*(lane+1)
        const unsigned S[4] = {above + s0, above + s1, above + s2, above + s3};
        unsigned packed = 0;
        bool found = false;
#pragma unroll
        for (int i = 0; i < 4; ++i) {
          const unsigned Sip1 = S[i] - h[i];
          if (S[i] >= krem && Sip1 < krem) {
            packed = ((unsigned)(4 * lane + i) << 16) | Sip1;
            found = true;
          }
        }
        const unsigned long long bm = __ballot(found);
        const int winner = __ffsll(bm) - 1;
        packed = (unsigned)__shfl((int)packed, winner, 64);
        const unsigned D = packed >> 16;
        krem -= (packed & 0xFFFFu);
        if (sh == 0) { T = lo + D; tie_need = krem; break; }
        lo += (D << sh);
        R = (1u << sh) - 1u;
      }
    }

    // final pass (register keys): sums over key > T, tie counts per group
    float vs = 0.f, ws = 0.f;
    unsigned cnt[4];
#pragma unroll
    for (int j = 0; j < 4; ++j) {
      cnt[j] = 0;
#pragma unroll
      for (int c = 0; c < 4; ++c) {
        const unsigned o = pk[4 * j + c];
        const unsigned oo[2] = {o & 0xFFFFu, o >> 16};
#pragma unroll
        for (int i = 0; i < 2; ++i) {
          const int g = 512 * j + 8 * lane + 2 * c + i;
          if (oo[i] > T) {
            const float pv = __expf(bf2f(ord2u16(oo[i])));
            vs += pv; ws += pv * fabsf((float)(g - frow));
          } else if (oo[i] == T) cnt[j]++;
        }
      }
    }
    const float ptie = __expf(bf2f(ord2u16(T)));

    // index-ordered tie selection: 16-bit-field scans (2 fields/word, <=512)
    unsigned pA = cnt[0] | (cnt[1] << 16), pB = cnt[2] | (cnt[3] << 16);
    unsigned iA = pA, iB = pB;
#pragma unroll
    for (int off = 1; off < 64; off <<= 1) {
      const unsigned vA = __shfl_up(iA, off, 64);
      const unsigned vB = __shfl_up(iB, off, 64);
      if (lane >= off) { iA += vA; iB += vB; }
    }
    const unsigned eA = iA - pA, eB = iB - pB;
    const unsigned tA = (unsigned)__shfl((int)iA, 63, 64);
    const unsigned tB = (unsigned)__shfl((int)iB, 63, 64);
    unsigned G[4];
    G[0] = 0;
    G[1] = G[0] + (tA & 0xFFFFu);
    G[2] = G[1] + (tA >> 16);
    G[3] = G[2] + (tB & 0xFFFFu);
#pragma unroll
    for (int j = 0; j < 4; ++j) {
      if (cnt[j]) {
        const unsigned off = (j < 2) ? ((eA >> (16 * j)) & 0xFFFFu)
                                     : ((eB >> (16 * (j - 2))) & 0xFFFFu);
        unsigned cc = 0;
#pragma unroll
        for (int c = 0; c < 4; ++c) {
          const unsigned o = pk[4 * j + c];
          const unsigned oo[2] = {o & 0xFFFFu, o >> 16};
#pragma unroll
          for (int i = 0; i < 2; ++i) {
            if (oo[i] == T) {
              if (G[j] + off + cc < tie_need) {
                const int g = 512 * j + 8 * lane + 2 * c + i;
                vs += ptie; ws += ptie * fabsf((float)(g - frow));
              }
              cc++;
            }
          }
        }
      }
    }

    vs = wave_sum(vs); ws = wave_sum(ws);
    if (lane == 0)
      C[(size_t)b * F_ + frow] = (ws / vs) * (1.f / (float)K_);
  }
}

// K3: cmin = min(C); out = mean(exp(-C + cmin - 1e-6)) (unchanged).
__global__ __launch_bounds__(1024) void final_kernel(
    const float* __restrict__ C, unsigned* __restrict__ out) {
  __shared__ float red[16];
  const int tid = threadIdx.x;
  const int wave = tid >> 6, lane = tid & 63;
  float v[32];
  float mn = 3.4e38f;
#pragma unroll
  for (int i = 0; i < 32; ++i) {
    v[i] = C[tid + 1024 * i];
    mn = fminf(mn, v[i]);
  }
  mn = -wave_max(-mn);
  if (lane == 0) red[wave] = mn;
  __syncthreads();
  float cmin = red[0];
  for (int w = 1; w < 16; ++w) cmin = fminf(cmin, red[w]);
  __syncthreads();
  float s = 0.f;
#pragma unroll
  for (int i = 0; i < 32; ++i) s += expf(cmin - v[i] - 1e-6f);
  s = wave_sum(s);
  if (lane == 0) red[wave] = s;
  __syncthreads();
  if (tid == 0) {
    float tot = 0.f;
    for (int w = 0; w < 16; ++w) tot += red[w];
    const float res = tot * (1.f / 32768.f);
    const __hip_bfloat16 hb = __float2bfloat16(res);
    const unsigned short u = *(const unsigned short*)&hb;
    out[0] = ((unsigned)u << 16) | (unsigned)u;
  }
}

extern "C" void kernel_launch(void* const* d_in, const int* in_sizes, int n_in,
                              void* d_out, int out_size, void* d_ws, size_t ws_size,
                              hipStream_t stream) {
  const float* X = (const float*)d_in[0];
  const float* M = (const float*)d_in[1];
  short* Xb16 = (short*)d_ws;                          // 4 MB (packed frags)
  short* Mb16 = Xb16 + (size_t)B_ * F_ * N_;           // 4 MB
  float* C = (float*)(Mb16 + (size_t)B_ * F_ * N_);    // 128 KB
  float* P = C + (size_t)B_ * F_;                      // 256 KB partial stats

  stats_kernel<<<dim3(B_ * 16), dim3(256), 0, stream>>>(X, M, P);
  normbf_kernel<<<dim3(B_ * 16), dim3(256), 0, stream>>>(X, M, P, Xb16, Mb16);
  rows_kernel<<<dim3(B_ * (F_ / 16)), dim3(512), 0, stream>>>(Xb16, Mb16, C);
  final_kernel<<<dim3(1), dim3(1024), 0, stream>>>(C, (unsigned*)d_out);
}